// Round 17
// baseline (1061.291 us; speedup 1.0000x reference)
//
#include <hip/hip_runtime.h>
#include <hip/hip_bf16.h>
#include <cstdint>
#include <cstddef>

#define N_ROWS 131072   // B*T
#define K_CB   1024
#define D_DIM  256
#define ND_TOT 33554432ull   // D*N
#define NK_TOT 134217728ull  // N*K
#define CHUNK  64

typedef __attribute__((ext_vector_type(8))) short short8;
typedef __attribute__((ext_vector_type(4))) float f32x4;
typedef __attribute__((address_space(3))) uint32_t lds_u32_t;
typedef const __attribute__((address_space(1))) uint32_t glb_u32_t;

static __device__ __forceinline__ float omd() { return (float)(1.0 - 0.99); }

static __device__ __forceinline__ float bf2f(ushort u) {
  union { uint32_t i; float f; } x; x.i = ((uint32_t)u) << 16; return x.f;
}
static __device__ __forceinline__ ushort f2bf(float f) {
  uint32_t x = __builtin_bit_cast(uint32_t, f);
  return (ushort)((x + 0x7fffu + ((x >> 16) & 1u)) >> 16);
}
// 2-way split: v ~= h + m (captures ~16 mantissa bits; residual ~2^-18 rel)
static __device__ __forceinline__ void split2(float v, ushort& h, ushort& m) {
  h = f2bf(v);
  m = f2bf(v - bf2f(h));
}

// ---------------- split A (+ fused xsq partial): in [D][N] -> aH/aM [N][D] ----
__global__ __launch_bounds__(256) void split_a_k(const float* __restrict__ in,
    ushort* __restrict__ aH, ushort* __restrict__ aM,
    float* __restrict__ xsq) {
  __shared__ float tile[128][65];
  __shared__ float part[4][64];
  int n0 = blockIdx.x * 64, d0 = blockIdx.y * 128;
  int lane = threadIdx.x & 63, grp = threadIdx.x >> 6;
  float ps = 0.f;
#pragma unroll
  for (int r = 0; r < 32; ++r) {
    int d = grp * 32 + r;
    float v = in[(size_t)(d0 + d) * N_ROWS + n0 + lane];
    tile[d][lane] = v;
    ps += v * v;
  }
  part[grp][lane] = ps;
  __syncthreads();
  if (grp == 0) {
    float s = part[0][lane] + part[1][lane] + part[2][lane] + part[3][lane];
    atomicAdd(&xsq[n0 + lane], s);
  }
#pragma unroll
  for (int r = 0; r < 16; ++r) {
    int nr = grp * 16 + r;
    float v0 = tile[lane * 2][nr], v1 = tile[lane * 2 + 1][nr];
    ushort h0, m0, h1, m1;
    split2(v0, h0, m0);
    split2(v1, h1, m1);
    size_t o = (size_t)(n0 + nr) * D_DIM + d0 + lane * 2;
    *(uint32_t*)&aH[o] = (uint32_t)h0 | ((uint32_t)h1 << 16);
    *(uint32_t*)&aM[o] = (uint32_t)m0 | ((uint32_t)m1 << 16);
  }
}

// ---------------- split B + esq (fused) ---------------------------------------
__global__ __launch_bounds__(256) void split_b_esq_k(const float* __restrict__ emb,
    ushort* __restrict__ bH, ushort* __restrict__ bM, float* __restrict__ esq) {
  int k = blockIdx.x * 4 + (threadIdx.x >> 6);
  int lane = threadIdx.x & 63;
  const float* er = emb + (size_t)k * D_DIM;
  float s = 0.f;
#pragma unroll
  for (int j = 0; j < 4; ++j) {
    float v = er[j * 64 + lane];
    ushort h, m;
    split2(v, h, m);
    bH[(size_t)k * D_DIM + j * 64 + lane] = h;
    bM[(size_t)k * D_DIM + j * 64 + lane] = m;
    s += v * v;
  }
  for (int off = 32; off; off >>= 1) s += __shfl_down(s, off);
  if (lane == 0) esq[k] = s;
}

// ---------------- MFMA distance GEMM: 256x256 tile, BK=64, 2-phase dbuf -------
// K_eff = 3 products x 256 = 768 -> 12 K-tiles. kt 0-3 (aH,bH), 4-7 (aH,bM),
// 8-11 (aM,bH). 512 thr = 8 waves (2Mx4N); wave tile 128x64 = acc[8][4].
// LDS 2 buf x 64 KB. chunk^(row&7) involutive swizzle (2-way = free).
// NEW: epilogue transposes dist through the (now-free) 128 KB LDS in two
// 256x128 passes -> fully-coalesced f32x4 nt stores (128B segments) instead
// of scalar 64B-segment stores. Argmin partials: 32 slots (per pass).
__global__ __launch_bounds__(512, 1) void mfma_dist_k(
    const ushort* __restrict__ aH, const ushort* __restrict__ aM,
    const ushort* __restrict__ bH, const ushort* __restrict__ bM,
    const float* __restrict__ xsq, const float* __restrict__ esq,
    float* __restrict__ dist, float* __restrict__ pminv, int* __restrict__ pmink) {
  extern __shared__ __align__(16) char lds[];   // 2 x 65536
  const int tid = threadIdx.x;
  const int wid = tid >> 6, l = tid & 63;
  const int l15 = l & 15, l4 = l >> 4;
  const int wm = wid >> 2, wn = wid & 3;

  // XCD swizzle (nwg = 2048, %8 == 0 -> bijective)
  int t0 = ((int)blockIdx.x & 7) * 256 + ((int)blockIdx.x >> 3);
  const int bx = t0 >> 2, by = t0 & 3;
  const int n0 = bx * 256, k0c = by * 256;

  // staging constants: 4 A + 4 B chunks of 16B per thread
  int gOff[4], lOffA[4], lOffB[4];
#pragma unroll
  for (int i = 0; i < 4; ++i) {
    int ch = i * 512 + tid;            // r = row 0..255, s = slot 0..7
    int r = ch >> 3, s = ch & 7;
    gOff[i] = r * 512 + ((s ^ (r & 7)) << 4);   // pre-swizzled source slot
    lOffA[i] = ch << 4;                // linear LDS dest
    lOffB[i] = 32768 + (ch << 4);
  }

  const char* aPl[2] = { (const char*)aH + (size_t)n0 * 512,
                         (const char*)aM + (size_t)n0 * 512 };
  const char* bPl[2] = { (const char*)bH + (size_t)k0c * 512,
                         (const char*)bM + (size_t)k0c * 512 };

  f32x4 acc[8][4];
#pragma unroll
  for (int mi = 0; mi < 8; ++mi)
#pragma unroll
    for (int ni = 0; ni < 4; ++ni)
#pragma unroll
      for (int e = 0; e < 4; ++e) acc[mi][ni][e] = 0.f;

#define STAGE(buf, kt)                                                          \
  {                                                                             \
    const char* pa = aPl[((kt) >> 3) & 1] + (((kt) & 3) << 7);                  \
    const char* pb = bPl[((kt) >> 2) & 1] + (((kt) & 3) << 7);                  \
    char* lb = lds + (buf) * 65536;                                             \
    _Pragma("unroll")                                                           \
    for (int i = 0; i < 4; ++i) {                                               \
      __builtin_amdgcn_global_load_lds((glb_u32_t*)(pa + gOff[i]),              \
          (lds_u32_t*)(lb + lOffA[i]), 16, 0, 0);                               \
      __builtin_amdgcn_global_load_lds((glb_u32_t*)(pb + gOff[i]),              \
          (lds_u32_t*)(lb + lOffB[i]), 16, 0, 0);                               \
    }                                                                           \
  }

#define COMPUTE(buf)                                                            \
  {                                                                             \
    const char* LA = lds + (buf) * 65536;                                       \
    const char* LB = LA + 32768;                                                \
    _Pragma("unroll")                                                           \
    for (int ks = 0; ks < 2; ++ks) {                                            \
      const int c = (ks << 2) + l4;                                             \
      short8 bfr[4];                                                            \
      _Pragma("unroll")                                                         \
      for (int ni = 0; ni < 4; ++ni) {                                          \
        int row = wn * 64 + ni * 16 + l15;                                      \
        bfr[ni] = *(const short8*)(LB + row * 128 + ((c ^ (row & 7)) << 4));    \
      }                                                                         \
      _Pragma("unroll")                                                         \
      for (int mi = 0; mi < 8; ++mi) {                                          \
        int row = wm * 128 + mi * 16 + l15;                                     \
        short8 af = *(const short8*)(LA + row * 128 + ((c ^ (row & 7)) << 4));  \
        _Pragma("unroll")                                                       \
        for (int ni = 0; ni < 4; ++ni)                                          \
          acc[mi][ni] = __builtin_amdgcn_mfma_f32_16x16x32_bf16(af, bfr[ni],    \
                                                                acc[mi][ni], 0, 0, 0); \
      }                                                                         \
    }                                                                           \
  }

  STAGE(0, 0);
  __syncthreads();
  for (int kt = 0; kt < 12; ++kt) {
    if (kt < 11) STAGE((kt + 1) & 1, kt + 1);
    COMPUTE(kt & 1);
    __syncthreads();
  }
#undef STAGE
#undef COMPUTE

  // ---- epilogue: dist via LDS transpose (2 passes of 256x128 f32 = 128 KB),
  //      coalesced f32x4 nt stores; argmin partials in 32 slots.
  float es[4];
#pragma unroll
  for (int ni = 0; ni < 4; ++ni) es[ni] = esq[k0c + wn * 64 + ni * 16 + l15];

#pragma unroll
  for (int p = 0; p < 2; ++p) {
    // write phase: dv into LDS [256 rows][32 chunks of 16B], c ^= (row&7)
#pragma unroll
    for (int mi = 0; mi < 8; ++mi) {
      float mv[4];
      int mk[4];
#pragma unroll
      for (int reg = 0; reg < 4; ++reg) { mv[reg] = INFINITY; mk[reg] = 0x7fffffff; }
#pragma unroll
      for (int reg = 0; reg < 4; ++reg) {
        int row = wm * 128 + mi * 16 + l4 * 4 + reg;
        float xs = xsq[n0 + row];
#pragma unroll
        for (int nj = 0; nj < 2; ++nj) {
          int ni = 2 * p + nj;
          int gcol = k0c + wn * 64 + ni * 16 + l15;
          float dv = xs + es[ni] - 2.f * acc[mi][ni][reg];
          int col = wn * 32 + nj * 16 + l15;
          int c = col >> 2;
          *(float*)(lds + row * 512 + ((c ^ (row & 7)) << 4) + (col & 3) * 4) = dv;
          if (dv < mv[reg]) { mv[reg] = dv; mk[reg] = gcol; }
        }
      }
#pragma unroll
      for (int off = 1; off < 16; off <<= 1) {
#pragma unroll
        for (int reg = 0; reg < 4; ++reg) {
          float ov = __shfl_xor(mv[reg], off);
          int ok = __shfl_xor(mk[reg], off);
          if (ov < mv[reg] || (ov == mv[reg] && ok < mk[reg])) { mv[reg] = ov; mk[reg] = ok; }
        }
      }
      if (l15 == 0) {
        int slot = by * 8 + wn * 2 + p;
#pragma unroll
        for (int reg = 0; reg < 4; ++reg) {
          int grow = n0 + wm * 128 + mi * 16 + l4 * 4 + reg;
          pminv[(size_t)slot * N_ROWS + grow] = mv[reg];
          pmink[(size_t)slot * N_ROWS + grow] = mk[reg];
        }
      }
    }
    __syncthreads();
    // read + coalesced nt store: per i, 16 rows x 32 chunks; per wave 1KB rows
#pragma unroll
    for (int i = 0; i < 16; ++i) {
      int id = i * 512 + tid;
      int row = id >> 5, c = id & 31;
      f32x4 v = *(const f32x4*)(lds + row * 512 + ((c ^ (row & 7)) << 4));
      int gcol = k0c + (c >> 3) * 64 + p * 32 + (c & 7) * 4;
      __builtin_nontemporal_store(v, (f32x4*)&dist[(size_t)(n0 + row) * K_CB + gcol]);
    }
    if (p == 0) __syncthreads();   // LDS reused by pass 1 writes
  }
}

// ---------------- finalize argmin + counts (fused; 32 partial slots) ----------
__global__ __launch_bounds__(256) void argc_k(const float* __restrict__ pminv,
                                              const int* __restrict__ pmink,
                                              int* __restrict__ idx, float* __restrict__ idxf,
                                              unsigned* __restrict__ counts) {
  __shared__ unsigned h[K_CB];
  for (int i = threadIdx.x; i < K_CB; i += 256) h[i] = 0;
  __syncthreads();
  int n = blockIdx.x * 256 + threadIdx.x;
  float mv = INFINITY;
  int mi = 0x7fffffff;
#pragma unroll
  for (int s = 0; s < 32; ++s) {
    float v = pminv[(size_t)s * N_ROWS + n];
    int k = pmink[(size_t)s * N_ROWS + n];
    if (v < mv || (v == mv && k < mi)) { mv = v; mi = k; }
  }
  idx[n] = mi;
  idxf[n] = (float)mi;
  atomicAdd(&h[mi], 1u);
  __syncthreads();
  for (int i = threadIdx.x; i < K_CB; i += 256) {
    unsigned v = h[i];
    if (v) atomicAdd(&counts[i], v);
  }
}

// ---------------- exclusive prefix sum ----------------------------------------
__global__ __launch_bounds__(1024) void prefix_k(const unsigned* __restrict__ counts,
                                                 int* __restrict__ start, int* __restrict__ cursor) {
  __shared__ int s[K_CB];
  int t = threadIdx.x;
  int v = (int)counts[t];
  s[t] = v;
  __syncthreads();
  for (int off = 1; off < K_CB; off <<= 1) {
    int x = (t >= off) ? s[t - off] : 0;
    __syncthreads();
    s[t] += x;
    __syncthreads();
  }
  int excl = s[t] - v;
  start[t] = excl;
  cursor[t] = excl;
  if (t == K_CB - 1) start[K_CB] = s[t];
}

// ---------------- scatter row ids ---------------------------------------------
__global__ __launch_bounds__(256) void scatter_k(const int* __restrict__ idx,
                                                 int* __restrict__ cursor, int* __restrict__ sorted) {
  int n = blockIdx.x * 256 + threadIdx.x;
  int pos = atomicAdd(&cursor[idx[n]], 1);
  sorted[pos] = n;
}

// ---------------- dw: balanced chunked segmented reduction --------------------
__global__ __launch_bounds__(256) void dwc_k(const ushort* __restrict__ aH,
                                             const ushort* __restrict__ aM,
                                             const int* __restrict__ sorted,
                                             const int* __restrict__ idx,
                                             float* __restrict__ dw) {
  __shared__ int s_n[CHUNK];
  __shared__ int s_k[CHUNK];
  int t = threadIdx.x;
  int r0 = blockIdx.x * CHUNK;
  if (t < CHUNK) {
    int n = sorted[r0 + t];
    s_n[t] = n;
    s_k[t] = idx[n];
  }
  __syncthreads();
  float acc = 0.f;
  for (int rb = 0; rb < CHUNK; rb += 8) {
    float v[8];
#pragma unroll
    for (int i = 0; i < 8; ++i) {
      size_t o = (size_t)s_n[rb + i] * D_DIM + t;
      v[i] = bf2f(aH[o]) + bf2f(aM[o]);
    }
#pragma unroll
    for (int i = 0; i < 8; ++i) {
      int r = rb + i;
      acc += v[i];
      if (r == CHUNK - 1 || s_k[r + 1] != s_k[r]) {
        atomicAdd(&dw[(size_t)s_k[r] * D_DIM + t], acc);
        acc = 0.f;
      }
    }
  }
}

// ---------------- one-hot writer (nontemporal; never re-read) -----------------
__global__ __launch_bounds__(256) void enc_k(const int* __restrict__ idx, float* __restrict__ enc) {
  int n = blockIdx.x * 2 + (threadIdx.x >> 7);
  int c = (threadIdx.x & 127) * 8;
  int k = idx[n];
  f32x4 a = {0.f, 0.f, 0.f, 0.f}, b = {0.f, 0.f, 0.f, 0.f};
  if (k >= c && k < c + 4) a[k - c] = 1.0f;
  else if (k >= c + 4 && k < c + 8) b[k - c - 4] = 1.0f;
  size_t o = (size_t)n * K_CB + c;
  __builtin_nontemporal_store(a, (f32x4*)&enc[o]);
  __builtin_nontemporal_store(b, (f32x4*)&enc[o + 4]);
}

// ---------------- new cluster sizes + perplexity ------------------------------
__global__ __launch_bounds__(1024) void newcs_k(const float* __restrict__ ema_cs,
                                                const unsigned* __restrict__ counts,
                                                float* __restrict__ out_ncs,
                                                float* __restrict__ out_perp) {
  __shared__ float s[1024];
  int k = threadIdx.x;
  float c = (float)counts[k];
  float raw = 0.99f * ema_cs[k] + omd() * c;
  s[k] = raw;
  __syncthreads();
  for (int off = 512; off; off >>= 1) { if (k < off) s[k] += s[k + off]; __syncthreads(); }
  float nsum = s[0];
  __syncthreads();
  out_ncs[k] = (raw + 1e-5f) / (nsum + (float)(1024 * 1e-5)) * nsum;
  float p = c * (1.0f / 131072.0f);
  float t = p * logf(p + 1e-10f);
  s[k] = t;
  __syncthreads();
  for (int off = 512; off; off >>= 1) { if (k < off) s[k] += s[k + off]; __syncthreads(); }
  if (k == 0) out_perp[0] = expf(-s[0]);
}

// ---------------- new ema_w + new embedding -----------------------------------
__global__ __launch_bounds__(256) void newemb_k(const float* __restrict__ ema_w,
                                                const float* __restrict__ dw,
                                                const float* __restrict__ ncs,
                                                float* __restrict__ out_nw,
                                                float* __restrict__ out_ne) {
  int i = blockIdx.x * 256 + threadIdx.x;
  int k = i >> 8;
  float nw = 0.99f * ema_w[i] + omd() * dw[i];
  out_nw[i] = nw;
  out_ne[i] = nw / ncs[k];
}

// ---------------- quantize + ST output + latent loss (f32x4, nt) --------------
__global__ __launch_bounds__(256) void quant_k(const float* __restrict__ in,
                                               const int* __restrict__ idx,
                                               const float* __restrict__ ne,
                                               float* __restrict__ qout,
                                               float* __restrict__ lossacc) {
  float lacc = 0.f;
  size_t stride = (size_t)gridDim.x * 256;
  for (size_t g = (size_t)blockIdx.x * 256 + threadIdx.x; g < (ND_TOT >> 2); g += stride) {
    size_t i = g << 2;
    int d = (int)(i >> 17);
    int n = (int)(i & (N_ROWS - 1));
    float4 x = *(const float4*)&in[i];
    int4 k4 = *(const int4*)&idx[n];
    float4 q;
    q.x = ne[(size_t)k4.x * D_DIM + d];
    q.y = ne[(size_t)k4.y * D_DIM + d];
    q.z = ne[(size_t)k4.z * D_DIM + d];
    q.w = ne[(size_t)k4.w * D_DIM + d];
    f32x4 o;
    o[0] = x.x + (q.x - x.x);
    o[1] = x.y + (q.y - x.y);
    o[2] = x.z + (q.z - x.z);
    o[3] = x.w + (q.w - x.w);
    __builtin_nontemporal_store(o, (f32x4*)&qout[i]);
    float dx = q.x - x.x, dy = q.y - x.y, dz = q.z - x.z, dwv = q.w - x.w;
    lacc += dx * dx + dy * dy + dz * dz + dwv * dwv;
  }
  for (int off = 32; off; off >>= 1) lacc += __shfl_down(lacc, off);
  __shared__ float w4[4];
  if ((threadIdx.x & 63) == 0) w4[threadIdx.x >> 6] = lacc;
  __syncthreads();
  if (threadIdx.x == 0) atomicAdd(lossacc, w4[0] + w4[1] + w4[2] + w4[3]);
}

__global__ void fin_k(const float* __restrict__ lossacc, float* __restrict__ out_loss) {
  out_loss[0] = 0.25f * lossacc[0] * (1.0f / 33554432.0f);
}

extern "C" void kernel_launch(void* const* d_in, const int* in_sizes, int n_in,
                              void* d_out, int out_size, void* d_ws, size_t ws_size,
                              hipStream_t stream) {
  const float* in     = (const float*)d_in[0];  // [D,B,T]
  const float* emb    = (const float*)d_in[1];  // [K,D]
  const float* ema_cs = (const float*)d_in[2];  // [K]
  const float* ema_w  = (const float*)d_in[3];  // [K,D]

  float* out = (float*)d_out;
  float* out_loss = out;                       // 1
  float* out_q    = out + 1;                   // 33554432
  float* out_perp = out + 33554433;            // 1
  float* out_enc  = out + 33554434;            // 134217728
  float* out_dist = out + 167772162;           // 134217728
  float* out_idx  = out + 301989890;           // 131072
  float* out_ncs  = out + 302120962;           // 1024
  float* out_nw   = out + 302121986;           // 262144
  float* out_ne   = out + 302384130;           // 262144

  char* w = (char*)d_ws;
  unsigned* counts  = (unsigned*)(w);              // 4 KiB
  float*    lossacc = (float*)(w + 4096);          // 4 B
  int*      cursor  = (int*)(w + 8192);            // 4 KiB
  int*      start   = (int*)(w + 12288);           // 1025 ints
  float*    xsq     = (float*)(w + 20480);         // 512 KiB (atomic-accumulated)
  float*    esq     = (float*)(w + 544768);        // 4 KiB
  int*      idx     = (int*)(w + 548864);          // 512 KiB
  int*      sorted  = (int*)(w + 1073152);         // 512 KiB
  float*    dw      = (float*)(w + 1597440);       // 1 MiB

  // bf16 planes + argmin partials (32 slots) live in out_enc region
  // (~162 MB of 512 MB), fully consumed BEFORE enc_k overwrites. +8 B align.
  ushort* aH = (ushort*)((char*)out_enc + 8);
  ushort* aM = aH + ND_TOT;
  ushort* bH = aM + ND_TOT;
  ushort* bM = bH + (K_CB * D_DIM);
  float*  pminv = (float*)(bM + (K_CB * D_DIM));   // [32][N]
  int*    pmink = (int*)(pminv + 32 * (size_t)N_ROWS);

  // zero counts/lossacc/cursor/start/xsq in one memset (ends exactly at esq)
  hipMemsetAsync(d_ws, 0, 544768, stream);
  hipMemsetAsync(dw, 0, K_CB * D_DIM * 4, stream);

  split_a_k<<<dim3(N_ROWS / 64, 2), 256, 0, stream>>>(in, aH, aM, xsq);
  split_b_esq_k<<<K_CB / 4, 256, 0, stream>>>(emb, bH, bM, esq);
  mfma_dist_k<<<(N_ROWS / 256) * (K_CB / 256), 512, 131072, stream>>>(
      aH, aM, bH, bM, xsq, esq, out_dist, pminv, pmink);
  argc_k<<<N_ROWS / 256, 256, 0, stream>>>(pminv, pmink, idx, out_idx, counts);
  prefix_k<<<1, 1024, 0, stream>>>(counts, start, cursor);
  scatter_k<<<N_ROWS / 256, 256, 0, stream>>>(idx, cursor, sorted);
  dwc_k<<<N_ROWS / CHUNK, 256, 0, stream>>>(aH, aM, sorted, idx, dw);
  enc_k<<<N_ROWS / 2, 256, 0, stream>>>(idx, out_enc);
  newcs_k<<<1, 1024, 0, stream>>>(ema_cs, counts, out_ncs, out_perp);
  newemb_k<<<K_CB * D_DIM / 256, 256, 0, stream>>>(ema_w, dw, out_ncs, out_nw, out_ne);
  quant_k<<<2048, 256, 0, stream>>>(in, idx, out_ne, out_q, lossacc);
  fin_k<<<1, 1, 0, stream>>>(lossacc, out_loss);
}

// Round 18
// 900.703 us; speedup vs baseline: 1.1783x; 1.1783x over previous
//
#include <hip/hip_runtime.h>
#include <hip/hip_bf16.h>
#include <cstdint>
#include <cstddef>

#define N_ROWS 131072   // B*T
#define K_CB   1024
#define D_DIM  256
#define ND_TOT 33554432ull   // D*N
#define NK_TOT 134217728ull  // N*K
#define CHUNK  64

typedef __attribute__((ext_vector_type(8))) short short8;
typedef __attribute__((ext_vector_type(4))) float f32x4;
typedef __attribute__((address_space(3))) uint32_t lds_u32_t;
typedef const __attribute__((address_space(1))) uint32_t glb_u32_t;

static __device__ __forceinline__ float omd() { return (float)(1.0 - 0.99); }

static __device__ __forceinline__ float bf2f(ushort u) {
  union { uint32_t i; float f; } x; x.i = ((uint32_t)u) << 16; return x.f;
}
static __device__ __forceinline__ ushort f2bf(float f) {
  uint32_t x = __builtin_bit_cast(uint32_t, f);
  return (ushort)((x + 0x7fffu + ((x >> 16) & 1u)) >> 16);
}
// 2-way split: v ~= h + m (captures ~16 mantissa bits; residual ~2^-18 rel)
static __device__ __forceinline__ void split2(float v, ushort& h, ushort& m) {
  h = f2bf(v);
  m = f2bf(v - bf2f(h));
}

// ---------------- split A (+ fused xsq partial): in [D][N] -> aH/aM [N][D] ----
__global__ __launch_bounds__(256) void split_a_k(const float* __restrict__ in,
    ushort* __restrict__ aH, ushort* __restrict__ aM,
    float* __restrict__ xsq) {
  __shared__ float tile[128][65];
  __shared__ float part[4][64];
  int n0 = blockIdx.x * 64, d0 = blockIdx.y * 128;
  int lane = threadIdx.x & 63, grp = threadIdx.x >> 6;
  float ps = 0.f;
#pragma unroll
  for (int r = 0; r < 32; ++r) {
    int d = grp * 32 + r;
    float v = in[(size_t)(d0 + d) * N_ROWS + n0 + lane];
    tile[d][lane] = v;
    ps += v * v;
  }
  part[grp][lane] = ps;
  __syncthreads();
  if (grp == 0) {
    float s = part[0][lane] + part[1][lane] + part[2][lane] + part[3][lane];
    atomicAdd(&xsq[n0 + lane], s);
  }
#pragma unroll
  for (int r = 0; r < 16; ++r) {
    int nr = grp * 16 + r;
    float v0 = tile[lane * 2][nr], v1 = tile[lane * 2 + 1][nr];
    ushort h0, m0, h1, m1;
    split2(v0, h0, m0);
    split2(v1, h1, m1);
    size_t o = (size_t)(n0 + nr) * D_DIM + d0 + lane * 2;
    *(uint32_t*)&aH[o] = (uint32_t)h0 | ((uint32_t)h1 << 16);
    *(uint32_t*)&aM[o] = (uint32_t)m0 | ((uint32_t)m1 << 16);
  }
}

// ---------------- split B + esq (fused) ---------------------------------------
__global__ __launch_bounds__(256) void split_b_esq_k(const float* __restrict__ emb,
    ushort* __restrict__ bH, ushort* __restrict__ bM, float* __restrict__ esq) {
  int k = blockIdx.x * 4 + (threadIdx.x >> 6);
  int lane = threadIdx.x & 63;
  const float* er = emb + (size_t)k * D_DIM;
  float s = 0.f;
#pragma unroll
  for (int j = 0; j < 4; ++j) {
    float v = er[j * 64 + lane];
    ushort h, m;
    split2(v, h, m);
    bH[(size_t)k * D_DIM + j * 64 + lane] = h;
    bM[(size_t)k * D_DIM + j * 64 + lane] = m;
    s += v * v;
  }
  for (int off = 32; off; off >>= 1) s += __shfl_down(s, off);
  if (lane == 0) esq[k] = s;
}

// ---------------- MFMA distance GEMM: 256x256 tile, BK=64, 2-phase dbuf -------
// K_eff = 3 products x 256 = 768 -> 12 K-tiles. kt 0-3 (aH,bH), 4-7 (aH,bM),
// 8-11 (aM,bH). 512 thr = 8 waves (2Mx4N); wave tile 128x64 = acc[8][4].
// LDS 2 buf x 64 KB. chunk^(row&7) involutive swizzle (2-way = free).
// dist written NONTEMPORAL (never re-read; scalar stores = 64B segments per
// 16-lane group, measured-best vs LDS-transpose variant which regressed).
__global__ __launch_bounds__(512, 1) void mfma_dist_k(
    const ushort* __restrict__ aH, const ushort* __restrict__ aM,
    const ushort* __restrict__ bH, const ushort* __restrict__ bM,
    const float* __restrict__ xsq, const float* __restrict__ esq,
    float* __restrict__ dist, float* __restrict__ pminv, int* __restrict__ pmink) {
  extern __shared__ __align__(16) char lds[];   // 2 x 65536
  const int tid = threadIdx.x;
  const int wid = tid >> 6, l = tid & 63;
  const int l15 = l & 15, l4 = l >> 4;
  const int wm = wid >> 2, wn = wid & 3;

  // XCD swizzle (nwg = 2048, %8 == 0 -> bijective)
  int t0 = ((int)blockIdx.x & 7) * 256 + ((int)blockIdx.x >> 3);
  const int bx = t0 >> 2, by = t0 & 3;
  const int n0 = bx * 256, k0c = by * 256;

  // staging constants: 4 A + 4 B chunks of 16B per thread
  int gOff[4], lOffA[4], lOffB[4];
#pragma unroll
  for (int i = 0; i < 4; ++i) {
    int ch = i * 512 + tid;            // r = row 0..255, s = slot 0..7
    int r = ch >> 3, s = ch & 7;
    gOff[i] = r * 512 + ((s ^ (r & 7)) << 4);   // pre-swizzled source slot
    lOffA[i] = ch << 4;                // linear LDS dest
    lOffB[i] = 32768 + (ch << 4);
  }

  const char* aPl[2] = { (const char*)aH + (size_t)n0 * 512,
                         (const char*)aM + (size_t)n0 * 512 };
  const char* bPl[2] = { (const char*)bH + (size_t)k0c * 512,
                         (const char*)bM + (size_t)k0c * 512 };

  f32x4 acc[8][4];
#pragma unroll
  for (int mi = 0; mi < 8; ++mi)
#pragma unroll
    for (int ni = 0; ni < 4; ++ni)
#pragma unroll
      for (int e = 0; e < 4; ++e) acc[mi][ni][e] = 0.f;

#define STAGE(buf, kt)                                                          \
  {                                                                             \
    const char* pa = aPl[((kt) >> 3) & 1] + (((kt) & 3) << 7);                  \
    const char* pb = bPl[((kt) >> 2) & 1] + (((kt) & 3) << 7);                  \
    char* lb = lds + (buf) * 65536;                                             \
    _Pragma("unroll")                                                           \
    for (int i = 0; i < 4; ++i) {                                               \
      __builtin_amdgcn_global_load_lds((glb_u32_t*)(pa + gOff[i]),              \
          (lds_u32_t*)(lb + lOffA[i]), 16, 0, 0);                               \
      __builtin_amdgcn_global_load_lds((glb_u32_t*)(pb + gOff[i]),              \
          (lds_u32_t*)(lb + lOffB[i]), 16, 0, 0);                               \
    }                                                                           \
  }

#define COMPUTE(buf)                                                            \
  {                                                                             \
    const char* LA = lds + (buf) * 65536;                                       \
    const char* LB = LA + 32768;                                                \
    _Pragma("unroll")                                                           \
    for (int ks = 0; ks < 2; ++ks) {                                            \
      const int c = (ks << 2) + l4;                                             \
      short8 bfr[4];                                                            \
      _Pragma("unroll")                                                         \
      for (int ni = 0; ni < 4; ++ni) {                                          \
        int row = wn * 64 + ni * 16 + l15;                                      \
        bfr[ni] = *(const short8*)(LB + row * 128 + ((c ^ (row & 7)) << 4));    \
      }                                                                         \
      _Pragma("unroll")                                                         \
      for (int mi = 0; mi < 8; ++mi) {                                          \
        int row = wm * 128 + mi * 16 + l15;                                     \
        short8 af = *(const short8*)(LA + row * 128 + ((c ^ (row & 7)) << 4));  \
        _Pragma("unroll")                                                       \
        for (int ni = 0; ni < 4; ++ni)                                          \
          acc[mi][ni] = __builtin_amdgcn_mfma_f32_16x16x32_bf16(af, bfr[ni],    \
                                                                acc[mi][ni], 0, 0, 0); \
      }                                                                         \
    }                                                                           \
  }

  STAGE(0, 0);
  __syncthreads();
  for (int kt = 0; kt < 12; ++kt) {
    if (kt < 11) STAGE((kt + 1) & 1, kt + 1);
    COMPUTE(kt & 1);
    __syncthreads();
  }
#undef STAGE
#undef COMPUTE

  // epilogue: distances (nontemporal) + per-wave argmin partials
  float es[4];
#pragma unroll
  for (int ni = 0; ni < 4; ++ni) es[ni] = esq[k0c + wn * 64 + ni * 16 + l15];
  const int slot = by * 4 + wn;

#pragma unroll
  for (int mi = 0; mi < 8; ++mi) {
    float mv[4];
    int mk[4];
#pragma unroll
    for (int reg = 0; reg < 4; ++reg) { mv[reg] = INFINITY; mk[reg] = 0x7fffffff; }
#pragma unroll
    for (int reg = 0; reg < 4; ++reg) {
      int grow = n0 + wm * 128 + mi * 16 + l4 * 4 + reg;
      float xs = xsq[grow];
#pragma unroll
      for (int ni = 0; ni < 4; ++ni) {
        int gcol = k0c + wn * 64 + ni * 16 + l15;
        float dv = xs + es[ni] - 2.f * acc[mi][ni][reg];
        __builtin_nontemporal_store(dv, &dist[(size_t)grow * K_CB + gcol]);
        if (dv < mv[reg]) { mv[reg] = dv; mk[reg] = gcol; }
      }
    }
#pragma unroll
    for (int off = 1; off < 16; off <<= 1) {
#pragma unroll
      for (int reg = 0; reg < 4; ++reg) {
        float ov = __shfl_xor(mv[reg], off);
        int ok = __shfl_xor(mk[reg], off);
        if (ov < mv[reg] || (ov == mv[reg] && ok < mk[reg])) { mv[reg] = ov; mk[reg] = ok; }
      }
    }
    if (l15 == 0) {
#pragma unroll
      for (int reg = 0; reg < 4; ++reg) {
        int grow = n0 + wm * 128 + mi * 16 + l4 * 4 + reg;
        pminv[(size_t)slot * N_ROWS + grow] = mv[reg];
        pmink[(size_t)slot * N_ROWS + grow] = mk[reg];
      }
    }
  }
}

// ---------------- finalize argmin + counts (fused) ----------------------------
__global__ __launch_bounds__(256) void argc_k(const float* __restrict__ pminv,
                                              const int* __restrict__ pmink,
                                              int* __restrict__ idx, float* __restrict__ idxf,
                                              unsigned* __restrict__ counts) {
  __shared__ unsigned h[K_CB];
  for (int i = threadIdx.x; i < K_CB; i += 256) h[i] = 0;
  __syncthreads();
  int n = blockIdx.x * 256 + threadIdx.x;
  float mv = INFINITY;
  int mi = 0x7fffffff;
#pragma unroll
  for (int s = 0; s < 16; ++s) {
    float v = pminv[(size_t)s * N_ROWS + n];
    int k = pmink[(size_t)s * N_ROWS + n];
    if (v < mv || (v == mv && k < mi)) { mv = v; mi = k; }
  }
  idx[n] = mi;
  idxf[n] = (float)mi;
  atomicAdd(&h[mi], 1u);
  __syncthreads();
  for (int i = threadIdx.x; i < K_CB; i += 256) {
    unsigned v = h[i];
    if (v) atomicAdd(&counts[i], v);
  }
}

// ---------------- exclusive prefix sum ----------------------------------------
__global__ __launch_bounds__(1024) void prefix_k(const unsigned* __restrict__ counts,
                                                 int* __restrict__ start, int* __restrict__ cursor) {
  __shared__ int s[K_CB];
  int t = threadIdx.x;
  int v = (int)counts[t];
  s[t] = v;
  __syncthreads();
  for (int off = 1; off < K_CB; off <<= 1) {
    int x = (t >= off) ? s[t - off] : 0;
    __syncthreads();
    s[t] += x;
    __syncthreads();
  }
  int excl = s[t] - v;
  start[t] = excl;
  cursor[t] = excl;
  if (t == K_CB - 1) start[K_CB] = s[t];
}

// ---------------- scatter row ids ---------------------------------------------
__global__ __launch_bounds__(256) void scatter_k(const int* __restrict__ idx,
                                                 int* __restrict__ cursor, int* __restrict__ sorted) {
  int n = blockIdx.x * 256 + threadIdx.x;
  int pos = atomicAdd(&cursor[idx[n]], 1);
  sorted[pos] = n;
}

// ---------------- dw: balanced chunked segmented reduction --------------------
__global__ __launch_bounds__(256) void dwc_k(const ushort* __restrict__ aH,
                                             const ushort* __restrict__ aM,
                                             const int* __restrict__ sorted,
                                             const int* __restrict__ idx,
                                             float* __restrict__ dw) {
  __shared__ int s_n[CHUNK];
  __shared__ int s_k[CHUNK];
  int t = threadIdx.x;
  int r0 = blockIdx.x * CHUNK;
  if (t < CHUNK) {
    int n = sorted[r0 + t];
    s_n[t] = n;
    s_k[t] = idx[n];
  }
  __syncthreads();
  float acc = 0.f;
  for (int rb = 0; rb < CHUNK; rb += 8) {
    float v[8];
#pragma unroll
    for (int i = 0; i < 8; ++i) {
      size_t o = (size_t)s_n[rb + i] * D_DIM + t;
      v[i] = bf2f(aH[o]) + bf2f(aM[o]);
    }
#pragma unroll
    for (int i = 0; i < 8; ++i) {
      int r = rb + i;
      acc += v[i];
      if (r == CHUNK - 1 || s_k[r + 1] != s_k[r]) {
        atomicAdd(&dw[(size_t)s_k[r] * D_DIM + t], acc);
        acc = 0.f;
      }
    }
  }
}

// ---------------- one-hot writer (nontemporal; never re-read) -----------------
__global__ __launch_bounds__(256) void enc_k(const int* __restrict__ idx, float* __restrict__ enc) {
  int n = blockIdx.x * 2 + (threadIdx.x >> 7);
  int c = (threadIdx.x & 127) * 8;
  int k = idx[n];
  f32x4 a = {0.f, 0.f, 0.f, 0.f}, b = {0.f, 0.f, 0.f, 0.f};
  if (k >= c && k < c + 4) a[k - c] = 1.0f;
  else if (k >= c + 4 && k < c + 8) b[k - c - 4] = 1.0f;
  size_t o = (size_t)n * K_CB + c;
  __builtin_nontemporal_store(a, (f32x4*)&enc[o]);
  __builtin_nontemporal_store(b, (f32x4*)&enc[o + 4]);
}

// ---------------- new cluster sizes + perplexity ------------------------------
__global__ __launch_bounds__(1024) void newcs_k(const float* __restrict__ ema_cs,
                                                const unsigned* __restrict__ counts,
                                                float* __restrict__ out_ncs,
                                                float* __restrict__ out_perp) {
  __shared__ float s[1024];
  int k = threadIdx.x;
  float c = (float)counts[k];
  float raw = 0.99f * ema_cs[k] + omd() * c;
  s[k] = raw;
  __syncthreads();
  for (int off = 512; off; off >>= 1) { if (k < off) s[k] += s[k + off]; __syncthreads(); }
  float nsum = s[0];
  __syncthreads();
  out_ncs[k] = (raw + 1e-5f) / (nsum + (float)(1024 * 1e-5)) * nsum;
  float p = c * (1.0f / 131072.0f);
  float t = p * logf(p + 1e-10f);
  s[k] = t;
  __syncthreads();
  for (int off = 512; off; off >>= 1) { if (k < off) s[k] += s[k + off]; __syncthreads(); }
  if (k == 0) out_perp[0] = expf(-s[0]);
}

// ---------------- new ema_w + new embedding -----------------------------------
__global__ __launch_bounds__(256) void newemb_k(const float* __restrict__ ema_w,
                                                const float* __restrict__ dw,
                                                const float* __restrict__ ncs,
                                                float* __restrict__ out_nw,
                                                float* __restrict__ out_ne) {
  int i = blockIdx.x * 256 + threadIdx.x;
  int k = i >> 8;
  float nw = 0.99f * ema_w[i] + omd() * dw[i];
  out_nw[i] = nw;
  out_ne[i] = nw / ncs[k];
}

// ---------------- quantize + ST output + latent loss (f32x4, nt) --------------
__global__ __launch_bounds__(256) void quant_k(const float* __restrict__ in,
                                               const int* __restrict__ idx,
                                               const float* __restrict__ ne,
                                               float* __restrict__ qout,
                                               float* __restrict__ lossacc) {
  float lacc = 0.f;
  size_t stride = (size_t)gridDim.x * 256;
  for (size_t g = (size_t)blockIdx.x * 256 + threadIdx.x; g < (ND_TOT >> 2); g += stride) {
    size_t i = g << 2;
    int d = (int)(i >> 17);
    int n = (int)(i & (N_ROWS - 1));
    float4 x = *(const float4*)&in[i];
    int4 k4 = *(const int4*)&idx[n];
    float4 q;
    q.x = ne[(size_t)k4.x * D_DIM + d];
    q.y = ne[(size_t)k4.y * D_DIM + d];
    q.z = ne[(size_t)k4.z * D_DIM + d];
    q.w = ne[(size_t)k4.w * D_DIM + d];
    f32x4 o;
    o[0] = x.x + (q.x - x.x);
    o[1] = x.y + (q.y - x.y);
    o[2] = x.z + (q.z - x.z);
    o[3] = x.w + (q.w - x.w);
    __builtin_nontemporal_store(o, (f32x4*)&qout[i]);
    float dx = q.x - x.x, dy = q.y - x.y, dz = q.z - x.z, dwv = q.w - x.w;
    lacc += dx * dx + dy * dy + dz * dz + dwv * dwv;
  }
  for (int off = 32; off; off >>= 1) lacc += __shfl_down(lacc, off);
  __shared__ float w4[4];
  if ((threadIdx.x & 63) == 0) w4[threadIdx.x >> 6] = lacc;
  __syncthreads();
  if (threadIdx.x == 0) atomicAdd(lossacc, w4[0] + w4[1] + w4[2] + w4[3]);
}

__global__ void fin_k(const float* __restrict__ lossacc, float* __restrict__ out_loss) {
  out_loss[0] = 0.25f * lossacc[0] * (1.0f / 33554432.0f);
}

extern "C" void kernel_launch(void* const* d_in, const int* in_sizes, int n_in,
                              void* d_out, int out_size, void* d_ws, size_t ws_size,
                              hipStream_t stream) {
  const float* in     = (const float*)d_in[0];  // [D,B,T]
  const float* emb    = (const float*)d_in[1];  // [K,D]
  const float* ema_cs = (const float*)d_in[2];  // [K]
  const float* ema_w  = (const float*)d_in[3];  // [K,D]

  float* out = (float*)d_out;
  float* out_loss = out;                       // 1
  float* out_q    = out + 1;                   // 33554432
  float* out_perp = out + 33554433;            // 1
  float* out_enc  = out + 33554434;            // 134217728
  float* out_dist = out + 167772162;           // 134217728
  float* out_idx  = out + 301989890;           // 131072
  float* out_ncs  = out + 302120962;           // 1024
  float* out_nw   = out + 302121986;           // 262144
  float* out_ne   = out + 302384130;           // 262144

  char* w = (char*)d_ws;
  unsigned* counts  = (unsigned*)(w);              // 4 KiB
  float*    lossacc = (float*)(w + 4096);          // 4 B
  int*      cursor  = (int*)(w + 8192);            // 4 KiB
  int*      start   = (int*)(w + 12288);           // 1025 ints
  float*    xsq     = (float*)(w + 20480);         // 512 KiB (atomic-accumulated)
  float*    esq     = (float*)(w + 544768);        // 4 KiB
  int*      idx     = (int*)(w + 548864);          // 512 KiB
  int*      sorted  = (int*)(w + 1073152);         // 512 KiB
  float*    dw      = (float*)(w + 1597440);       // 1 MiB

  // bf16 planes + argmin partials live in out_enc region (~146 MB of 512 MB),
  // fully consumed BEFORE enc_k overwrites the region. +8 B -> 16B alignment.
  ushort* aH = (ushort*)((char*)out_enc + 8);
  ushort* aM = aH + ND_TOT;
  ushort* bH = aM + ND_TOT;
  ushort* bM = bH + (K_CB * D_DIM);
  float*  pminv = (float*)(bM + (K_CB * D_DIM));   // [16][N]
  int*    pmink = (int*)(pminv + 16 * (size_t)N_ROWS);

  // zero counts/lossacc/cursor/start/xsq in one memset (ends exactly at esq)
  hipMemsetAsync(d_ws, 0, 544768, stream);
  hipMemsetAsync(dw, 0, K_CB * D_DIM * 4, stream);

  split_a_k<<<dim3(N_ROWS / 64, 2), 256, 0, stream>>>(in, aH, aM, xsq);
  split_b_esq_k<<<K_CB / 4, 256, 0, stream>>>(emb, bH, bM, esq);
  mfma_dist_k<<<(N_ROWS / 256) * (K_CB / 256), 512, 131072, stream>>>(
      aH, aM, bH, bM, xsq, esq, out_dist, pminv, pmink);
  argc_k<<<N_ROWS / 256, 256, 0, stream>>>(pminv, pmink, idx, out_idx, counts);
  prefix_k<<<1, 1024, 0, stream>>>(counts, start, cursor);
  scatter_k<<<N_ROWS / 256, 256, 0, stream>>>(idx, cursor, sorted);
  dwc_k<<<N_ROWS / CHUNK, 256, 0, stream>>>(aH, aM, sorted, idx, dw);
  enc_k<<<N_ROWS / 2, 256, 0, stream>>>(idx, out_enc);
  newcs_k<<<1, 1024, 0, stream>>>(ema_cs, counts, out_ncs, out_perp);
  newemb_k<<<K_CB * D_DIM / 256, 256, 0, stream>>>(ema_w, dw, out_ncs, out_nw, out_ne);
  quant_k<<<2048, 256, 0, stream>>>(in, idx, out_ne, out_q, lossacc);
  fin_k<<<1, 1, 0, stream>>>(lossacc, out_loss);
}